// Round 4
// baseline (108.714 us; speedup 1.0000x reference)
//
#include <hip/hip_runtime.h>
#include <hip/hip_bf16.h>
#include <stdint.h>

#define B_DIM 16384
#define H_DIM 512
#define KTOT  1024   // I + H
#define NP    2048   // 4 gates * H

typedef __attribute__((ext_vector_type(8))) short short8;
typedef __attribute__((ext_vector_type(4))) float floatx4;

static __device__ __forceinline__ unsigned short f2bf(float f) {
  unsigned int u = __float_as_uint(f);
  u += 0x7fffu + ((u >> 16) & 1u);
  return (unsigned short)(u >> 16);
}

static __device__ __forceinline__ short8 cvt8(floatx4 v0, floatx4 v1) {
  short8 o;
#pragma unroll
  for (int i = 0; i < 4; ++i) {
    o[i]     = (short)f2bf(v0[i]);
    o[i + 4] = (short)f2bf(v1[i]);
  }
  return o;
}

// ---------------------------------------------------------------------------
// Packed A (bf16): [bm(64)][kt(16)][mh(2)][wr(2)][m4(4)][kk(2)][lane(64)][8]
//   row = bm*256 + wr*128 + mh*64 + m4*16 + (lane&15)
//   k   = kt*64 + kk*32 + (lane>>4)*8      (k<512 -> x, else z)
// ---------------------------------------------------------------------------
__global__ __launch_bounds__(256) void pack_a_kernel(
    const float* __restrict__ x, const float* __restrict__ z,
    unsigned short* __restrict__ Ap) {
  int u    = blockIdx.x * 256 + threadIdx.x;
  int lane = u & 63;
  int kk   = (u >> 6) & 1;
  int m4   = (u >> 7) & 3;
  int wr   = (u >> 9) & 1;
  int mh   = (u >> 10) & 1;
  int kt   = (u >> 11) & 15;
  int bm   = u >> 15;
  int row  = bm * 256 + wr * 128 + mh * 64 + m4 * 16 + (lane & 15);
  int k    = kt * 64 + kk * 32 + ((lane >> 4) << 3);
  const float* src = (k < 512) ? (x + (uint64_t)row * 512 + k)
                               : (z + (uint64_t)row * 512 + (k - 512));
  floatx4 v0 = *reinterpret_cast<const floatx4*>(src);
  floatx4 v1 = *reinterpret_cast<const floatx4*>(src + 4);
  *reinterpret_cast<short8*>(Ap + (uint64_t)u * 8) = cvt8(v0, v1);
}

// ---------------------------------------------------------------------------
// Packed B (bf16): [bn(8)][kt(16)][nh(2)][wc(4)][n2(2)][kk(2)][lane(64)][8]
//   h = bn*64 + wc*16 + (lane&15); gate g = nh*2 + n2
//   k = kt*64 + kk*32 + (lane>>4)*8    (k<512 -> W_g, else U_g)
// ---------------------------------------------------------------------------
__global__ __launch_bounds__(256) void pack_w_kernel(
    const float* __restrict__ Wi, const float* __restrict__ Wf,
    const float* __restrict__ Wc, const float* __restrict__ Wo,
    const float* __restrict__ Ui, const float* __restrict__ Uf,
    const float* __restrict__ Uc, const float* __restrict__ Uo,
    unsigned short* __restrict__ Bp) {
  int u    = blockIdx.x * 256 + threadIdx.x;
  int lane = u & 63;
  int kk   = (u >> 6) & 1;
  int n2   = (u >> 7) & 1;
  int wc   = (u >> 8) & 3;
  int nh   = (u >> 10) & 1;
  int kt   = (u >> 11) & 15;
  int bn   = u >> 15;
  int h    = bn * 64 + wc * 16 + (lane & 15);
  int g    = nh * 2 + n2;
  int k    = kt * 64 + kk * 32 + ((lane >> 4) << 3);
  const float* src;
  if (k < 512) {
    const float* W = (g == 0) ? Wi : (g == 1) ? Wf : (g == 2) ? Wc : Wo;
    src = W + (uint64_t)h * 512 + k;
  } else {
    const float* U = (g == 0) ? Ui : (g == 1) ? Uf : (g == 2) ? Uc : Uo;
    src = U + (uint64_t)h * 512 + (k - 512);
  }
  floatx4 v0 = *reinterpret_cast<const floatx4*>(src);
  floatx4 v1 = *reinterpret_cast<const floatx4*>(src + 4);
  *reinterpret_cast<short8*>(Bp + (uint64_t)u * 8) = cvt8(v0, v1);
}

// stage one 16KB half-tile: 512 threads x 16B x 2 instructions
static __device__ __forceinline__ void stage2(const unsigned short* g,
                                              unsigned short* l, int tid) {
  __builtin_amdgcn_global_load_lds(
      (const __attribute__((address_space(1))) void*)(g + tid * 8),
      (__attribute__((address_space(3))) void*)(l + tid * 8), 16, 0, 0);
  __builtin_amdgcn_global_load_lds(
      (const __attribute__((address_space(1))) void*)(g + 4096 + tid * 8),
      (__attribute__((address_space(3))) void*)(l + 4096 + tid * 8), 16, 0, 0);
}

// ---- phase skeleton pieces (m201 template) ----
#define READS_A(OFF)                                                        \
  _Pragma("unroll")                                                         \
  for (int m4 = 0; m4 < 4; ++m4) {                                          \
    aF[m4][0] = *reinterpret_cast<const short8*>(aC + (OFF) + m4 * 1024);   \
    aF[m4][1] = *reinterpret_cast<const short8*>(aC + (OFF) + m4 * 1024 + 512); \
  }
#define READS_B(OFF)                                                        \
  _Pragma("unroll")                                                         \
  for (int n2 = 0; n2 < 2; ++n2) {                                          \
    bF[n2][0] = *reinterpret_cast<const short8*>(bC + (OFF) + n2 * 1024);   \
    bF[n2][1] = *reinterpret_cast<const short8*>(bC + (OFF) + n2 * 1024 + 512); \
  }
// barrier -> lgkmcnt(0) -> (fenced) pure MFMA cluster
#define PREBAR                                                              \
  __builtin_amdgcn_sched_barrier(0);                                        \
  __builtin_amdgcn_s_barrier();                                             \
  asm volatile("s_waitcnt lgkmcnt(0)" ::: "memory");                        \
  __builtin_amdgcn_sched_barrier(0);
#define CLUSTER(MB, NB)                                                     \
  __builtin_amdgcn_s_setprio(1);                                            \
  _Pragma("unroll")                                                         \
  for (int m4 = 0; m4 < 4; ++m4)                                            \
    _Pragma("unroll")                                                       \
    for (int n2 = 0; n2 < 2; ++n2)                                          \
      _Pragma("unroll")                                                     \
      for (int kk = 0; kk < 2; ++kk)                                        \
        acc[(MB) + m4][(NB) + n2] = __builtin_amdgcn_mfma_f32_16x16x32_bf16(\
            aF[m4][kk], bF[n2][kk], acc[(MB) + m4][(NB) + n2], 0, 0, 0);    \
  __builtin_amdgcn_s_setprio(0);                                            \
  __builtin_amdgcn_sched_barrier(0);
#define POSTBAR_W(N)                                                        \
  asm volatile("s_waitcnt vmcnt(" #N ")" ::: "memory");                     \
  __builtin_amdgcn_sched_barrier(0);                                        \
  __builtin_amdgcn_s_barrier();                                             \
  __builtin_amdgcn_sched_barrier(0);
#define POSTBAR                                                             \
  __builtin_amdgcn_s_barrier();                                             \
  __builtin_amdgcn_sched_barrier(0);

// ---------------------------------------------------------------------------
// GEMM M=16384 Np=2048 K=1024, 256x256 tile, BK=64, 8 waves (2Mx4N),
// 4 quadrant-phases/K-tile, two barriers/phase, counted vmcnt (never 0 in
// main loop), double-buffered 128KB LDS. Halves issued one per phase:
//   p0:A-lo(kt+1) p1:B-lo(kt+1) p2:A-hi(kt+1) p3:B-hi(kt+1)
// Waits: end-p0/p1/p3 vmcnt(4); end-p2 none. Tail tile: 2, 0, none.
// ---------------------------------------------------------------------------
__global__ __launch_bounds__(512, 2) void lstm_gemm_kernel(
    const unsigned short* __restrict__ Ap,
    const unsigned short* __restrict__ Bp,
    const float* __restrict__ z,
    const float* __restrict__ b_i, const float* __restrict__ b_f,
    const float* __restrict__ b_c, const float* __restrict__ b_o,
    float* __restrict__ out) {
  __shared__ unsigned short lds[65536];  // 128KB: [buf(2)][A 16384 | B 16384]

  int tid  = threadIdx.x;
  int bid  = blockIdx.x;
  int sw   = (bid & 7) * 64 + (bid >> 3);  // 512 % 8 == 0 -> bijective
  int bn   = sw & 7;
  int bm   = sw >> 3;
  int lane = tid & 63;
  int wid  = tid >> 6;
  int wr   = wid >> 2;   // 0..1 -> 128 rows
  int wc   = wid & 3;    // 0..3 -> 16 h * 4 gates

  floatx4 acc[8][4];
#pragma unroll
  for (int m = 0; m < 8; ++m)
#pragma unroll
    for (int g = 0; g < 4; ++g)
      acc[m][g] = (floatx4){0.f, 0.f, 0.f, 0.f};

  const unsigned short* gA = Ap + (uint64_t)bm * (16 * 16384);
  const unsigned short* gB = Bp + (uint64_t)bn * (16 * 16384);
  const unsigned short* aRd = lds + wr * 4096 + lane * 8;
  const unsigned short* bRd = lds + 16384 + wc * 2048 + lane * 8;

  // prologue: tile 0 -> buf0 (A-lo, B-lo, A-hi, B-hi)
  stage2(gA, lds, tid);
  stage2(gB, lds + 16384, tid);
  stage2(gA + 8192, lds + 8192, tid);
  stage2(gB + 8192, lds + 24576, tid);
  asm volatile("s_waitcnt vmcnt(4)" ::: "memory");
  __builtin_amdgcn_sched_barrier(0);
  __builtin_amdgcn_s_barrier();
  __builtin_amdgcn_sched_barrier(0);

  int curOff = 0;
  short8 aF[4][2], bF[2][2];

#pragma unroll 1
  for (int kt = 0; kt < 15; ++kt) {
    const int nxtOff = curOff ^ 32768;
    const unsigned short* aC = aRd + curOff;
    const unsigned short* bC = bRd + curOff;
    unsigned short* aN = lds + nxtOff;
    unsigned short* bN = lds + nxtOff + 16384;
    const unsigned short* gAn = gA + (kt + 1) * 16384;
    const unsigned short* gBn = gB + (kt + 1) * 16384;

    // phase 0: quadrant (m-lo, n-lo)
    READS_A(0) READS_B(0)
    stage2(gAn, aN, tid);
    asm volatile("s_waitcnt lgkmcnt(8)" ::: "memory");  // 12 reads this phase
    PREBAR CLUSTER(0, 0) POSTBAR_W(4)

    // phase 1: quadrant (m-hi, n-lo): reload A-hi, reuse B
    READS_A(8192)
    stage2(gBn, bN, tid);
    PREBAR CLUSTER(4, 0) POSTBAR_W(4)

    // phase 2: quadrant (m-hi, n-hi): reuse A, reload B-hi
    READS_B(8192)
    stage2(gAn + 8192, aN + 8192, tid);
    PREBAR CLUSTER(4, 2) POSTBAR

    // phase 3: quadrant (m-lo, n-hi): reload A-lo, reuse B
    READS_A(0)
    stage2(gBn + 8192, bN + 8192, tid);
    PREBAR CLUSTER(0, 2) POSTBAR_W(4)

    curOff = nxtOff;
  }

  // ---- tail tile (kt = 15): no staging; drain 2 -> 0
  {
    const unsigned short* aC = aRd + curOff;
    const unsigned short* bC = bRd + curOff;

    READS_A(0) READS_B(0)
    asm volatile("s_waitcnt lgkmcnt(8)" ::: "memory");
    PREBAR CLUSTER(0, 0) POSTBAR_W(2)

    READS_A(8192)
    PREBAR CLUSTER(4, 0) POSTBAR_W(0)

    READS_B(8192)
    PREBAR CLUSTER(4, 2) POSTBAR

    READS_A(0)
    PREBAR CLUSTER(0, 2)
  }

  // ---- fused LSTM epilogue (lane-local: acc frag index g == gate)
  int h = bn * 64 + wc * 16 + (lane & 15);
  float vbi = b_i[h], vbf = b_f[h], vbc = b_c[h], vbo = b_o[h];
  int rbase = bm * 256 + wr * 128 + ((lane >> 4) << 2);
  float* outH = out;
  float* outC = out + (uint64_t)B_DIM * H_DIM;
#pragma unroll
  for (int m = 0; m < 8; ++m) {
#pragma unroll
    for (int j = 0; j < 4; ++j) {
      int r = rbase + m * 16 + j;
      float pi = acc[m][0][j] + vbi;
      float pf = acc[m][1][j] + vbf;
      float pc = acc[m][2][j] + vbc;
      float po = acc[m][3][j] + vbo;
      float gi = 1.f / (1.f + __expf(-pi));
      float gf = 1.f / (1.f + __expf(-pf));
      float gc = 1.f - 2.f / (__expf(2.f * pc) + 1.f);  // tanh
      float go = 1.f / (1.f + __expf(-po));
      float zv = z[(uint64_t)r * H_DIM + h];
      float cn = gf * zv + gi * gc;
      float hn = go * (1.f - 2.f / (__expf(2.f * cn) + 1.f));
      outH[(uint64_t)r * H_DIM + h] = hn;
      outC[(uint64_t)r * H_DIM + h] = cn;
    }
  }
}

extern "C" void kernel_launch(void* const* d_in, const int* in_sizes, int n_in,
                              void* d_out, int out_size, void* d_ws, size_t ws_size,
                              hipStream_t stream) {
  const float* z  = (const float*)d_in[0];
  const float* x  = (const float*)d_in[1];
  const float* Wi = (const float*)d_in[2];
  const float* Wf = (const float*)d_in[3];
  const float* Wc = (const float*)d_in[4];
  const float* Wo = (const float*)d_in[5];
  const float* bi = (const float*)d_in[6];
  const float* bf = (const float*)d_in[7];
  const float* bc = (const float*)d_in[8];
  const float* bo = (const float*)d_in[9];
  const float* Ui = (const float*)d_in[10];
  const float* Uf = (const float*)d_in[11];
  const float* Uc = (const float*)d_in[12];
  const float* Uo = (const float*)d_in[13];

  unsigned short* Ap = (unsigned short*)d_ws;                          // 32 MB
  unsigned short* Bp = (unsigned short*)((char*)d_ws
                        + (size_t)B_DIM * KTOT * sizeof(unsigned short)); // +4 MB
  float* out = (float*)d_out;

  hipLaunchKernelGGL(pack_w_kernel, dim3((size_t)NP * KTOT / 8 / 256), dim3(256), 0, stream,
                     Wi, Wf, Wc, Wo, Ui, Uf, Uc, Uo, Bp);
  hipLaunchKernelGGL(pack_a_kernel, dim3((size_t)B_DIM * KTOT / 8 / 256), dim3(256), 0, stream,
                     x, z, Ap);
  hipLaunchKernelGGL(lstm_gemm_kernel, dim3(512), dim3(512), 0, stream,
                     Ap, Bp, z, bi, bf, bc, bo, out);
}